// Round 3
// baseline (894.859 us; speedup 1.0000x reference)
//
#include <hip/hip_runtime.h>
#include <math.h>

// B=8, N=40962, D=40, H=512, D_DYN=32, 4 steps, dt=0.1
constexpr int BB   = 8;
constexpr int NN   = 40962;
constexpr int DDIM = 40;
constexpr int HH   = 512;
constexpr int DDYN = 32;
constexpr float STEPSZ = 0.1f;

constexpr int TM   = 64;      // nodes per block
constexpr int NTHR = 512;     // 8 waves
constexpr int ZS   = 168;     // z LDS row stride (bf16 elems)

constexpr size_t X_ELEMS = (size_t)BB * NN * DDIM;
constexpr size_t X_BYTES = X_ELEMS * 4;
constexpr int W1P_ELEMS = 32 * 5 * 64 * 8;   // 81920  [mt][kk][lane][j] A-frags
constexpr int W2P_ELEMS = 2 * 16 * 64 * 8;   // 16384  [jt][kk][lane][j] A-frags

typedef __attribute__((ext_vector_type(8))) short short8;
typedef __attribute__((ext_vector_type(4))) float f32x4;
typedef __attribute__((ext_vector_type(4))) unsigned short u16x4;

__device__ __forceinline__ unsigned short bf16_rne(float f) {
    unsigned int u = __float_as_uint(f);
    unsigned int r = (u + 0x7FFFu + ((u >> 16) & 1u)) >> 16;
    return (unsigned short)r;
}

__device__ __forceinline__ unsigned int pk_bf16(float a, float b) {
#if __has_builtin(__builtin_amdgcn_cvt_pk_bf16_f32)
    auto v = __builtin_amdgcn_cvt_pk_bf16_f32(a, b);
    unsigned int r;
    __builtin_memcpy(&r, &v, 4);
    return r;
#else
    return (unsigned int)bf16_rne(a) | ((unsigned int)bf16_rne(b) << 16);
#endif
}

__device__ __forceinline__ float gelu_fast(float x) {
    // 0.5x(1+tanh(c(x+0.044715x^3))) == x * sigmoid(2c(x+0.044715x^3))
    float u = x * fmaf(0.044715f, x * x, 1.0f);
    float e = __expf(-1.5957691216057308f * u);
    return x * __builtin_amdgcn_rcpf(1.0f + e);
}

// ---- A-position fragment packing ----
// W1p[t], t = ((mt*5+kk)*64 + lane)*8 + j ; A[m=mt*16+nl][k=kk*32+q*8+j] = W1[k][m]
__global__ __launch_bounds__(256) void pack_w1(const float* __restrict__ W1,
                                               unsigned short* __restrict__ W1p) {
    int t = blockIdx.x * 256 + threadIdx.x;
    if (t >= W1P_ELEMS) return;
    int j = t & 7, ln = (t >> 3) & 63, g = t >> 9;
    int kk = g % 5, mt = g / 5;
    int nl = ln & 15, q = ln >> 4;
    int k = kk * 32 + q * 8 + j, m = mt * 16 + nl;
    W1p[t] = bf16_rne(W1[(size_t)k * HH + m]);
}
// W2p[t], t = ((jt*16+kk)*64 + lane)*8 + j ; A[m=jt*16+nl][k=kk*32+q*8+j] = W2[k][m]
__global__ __launch_bounds__(256) void pack_w2(const float* __restrict__ W2,
                                               unsigned short* __restrict__ W2p) {
    int t = blockIdx.x * 256 + threadIdx.x;
    if (t >= W2P_ELEMS) return;
    int j = t & 7, ln = (t >> 3) & 63, g = t >> 9;
    int kk = g & 15, jt = g >> 4;
    int nl = ln & 15, q = ln >> 4;
    int k = kk * 32 + q * 8 + j, m = jt * 16 + nl;
    W2p[t] = bf16_rne(W2[(size_t)k * DDYN + m]);
}

// h LDS: 64 nodes x 512 bf16 = 64KB, XOR-swizzled 16B chunks:
// elem(node, hid) = node*512 + (((hid>>3) ^ (node&7))<<3) + (hid&7)
__global__ __launch_bounds__(NTHR, 4) void step_mfma(
    const float* __restrict__ xsrc, float* __restrict__ xdst,
    const int* __restrict__ index,
    const unsigned short* __restrict__ W1p, const float* __restrict__ b1,
    const unsigned short* __restrict__ W2p, const float* __restrict__ b2)
{
    __shared__ alignas(16) unsigned short smem[TM * HH];  // 64 KiB; z overlays front
    unsigned short* z = smem;   // [64][ZS], dead after GEMM1
    unsigned short* h = smem;   // [64][512] swizzled

    const int tid = threadIdx.x;
    const int w   = tid >> 6;
    const int ln  = tid & 63;
    const int nl  = ln & 15;
    const int q   = ln >> 4;
    const int bid = blockIdx.x;
    const int b   = bid & 7;            // XCD-affine batch
    const int n0  = (bid >> 3) * TM;
    const size_t xbase = (size_t)b * NN * DDIM;

    // ---- Phase 1: gather -> z (bf16) ----
    for (int e = tid; e < TM * 4 * 10; e += NTHR) {
        int m = e / 40, r = e - m * 40;
        int k = r / 10, qq = r - k * 10;
        u16x4 out = (u16x4)0;
        int n = n0 + m;
        if (n < NN) {
            int nb = index[n * 4 + k];
            const float4* src = (const float4*)(xsrc + xbase + (size_t)nb * DDIM);
            float4 v = src[qq];
            out.x = bf16_rne(v.x); out.y = bf16_rne(v.y);
            out.z = bf16_rne(v.z); out.w = bf16_rne(v.w);
        }
        *(u16x4*)(z + m * ZS + k * 40 + qq * 4) = out;
    }
    __syncthreads();

    // ---- Phase 2: GEMM1  h^T = W1^T (A) . z^T (B) ----
    // wave w owns hidden tiles mt_glob = w*4..w*4+3, all 4 node tiles
    f32x4 acc[4][4];   // [mt][nt]; lane: row(hidden)=q*4+i, col(node)=nl
    #pragma unroll
    for (int mt = 0; mt < 4; ++mt) {
        float4 bv = *(const float4*)(b1 + (w * 4 + mt) * 16 + q * 4);
        f32x4 a; a[0] = bv.x; a[1] = bv.y; a[2] = bv.z; a[3] = bv.w;
        #pragma unroll
        for (int nt = 0; nt < 4; ++nt) acc[mt][nt] = a;
    }
    for (int kk = 0; kk < 5; ++kk) {
        short8 bfr[4];
        #pragma unroll
        for (int nt = 0; nt < 4; ++nt)
            bfr[nt] = *(const short8*)(z + (nt * 16 + nl) * ZS + kk * 32 + q * 8);
        #pragma unroll
        for (int mt = 0; mt < 4; ++mt) {
            short8 afr = *(const short8*)(W1p + (size_t)(((w * 4 + mt) * 5 + kk) * 512 + ln * 8));
            #pragma unroll
            for (int nt = 0; nt < 4; ++nt)
                acc[mt][nt] = __builtin_amdgcn_mfma_f32_16x16x32_bf16(afr, bfr[nt], acc[mt][nt], 0, 0, 0);
        }
    }
    __syncthreads();   // z dead; safe to overwrite with h

    // ---- Phase 3: h = gelu(acc), packed b64 writes ----
    #pragma unroll
    for (int mt = 0; mt < 4; ++mt) {
        const int hid = (w * 4 + mt) * 16 + q * 4;   // 4 consecutive hidden
        #pragma unroll
        for (int nt = 0; nt < 4; ++nt) {
            f32x4 a = acc[mt][nt];
            unsigned int p0 = pk_bf16(gelu_fast(a[0]), gelu_fast(a[1]));
            unsigned int p1 = pk_bf16(gelu_fast(a[2]), gelu_fast(a[3]));
            int node = nt * 16 + nl;
            int chunk = (hid >> 3) ^ (node & 7);
            uint2 val; val.x = p0; val.y = p1;
            *(uint2*)(h + node * 512 + chunk * 8 + (hid & 7)) = val;
        }
    }
    __syncthreads();

    // ---- Phase 4: GEMM2  fz^T = W2^T (A) . h^T (B) ----
    const int jt = w >> 2, nt2 = w & 3;
    f32x4 acc2;
    {
        float4 bv = *(const float4*)(b2 + jt * 16 + q * 4);
        acc2[0] = bv.x; acc2[1] = bv.y; acc2[2] = bv.z; acc2[3] = bv.w;
    }
    const int hrow = nt2 * 16 + nl;
    #pragma unroll
    for (int kk = 0; kk < 16; ++kk) {
        short8 afr = *(const short8*)(W2p + (size_t)(((jt * 16 + kk) * 64 + ln) * 8));
        int chunk = (kk * 4 + q) ^ (hrow & 7);
        short8 bfr = *(const short8*)(h + hrow * 512 + chunk * 8);
        acc2 = __builtin_amdgcn_mfma_f32_16x16x32_bf16(afr, bfr, acc2, 0, 0, 0);
    }

    // ---- Phase 5: epilogue. lane holds fz[node=hrow][j=jt*16+q*4+i] ----
    {
        int n = n0 + hrow;
        if (n < NN) {
            size_t off = xbase + (size_t)n * DDIM + jt * 16 + q * 4;
            float4 v = *(const float4*)(xsrc + off);
            v.x = fmaf(STEPSZ, acc2[0], v.x);
            v.y = fmaf(STEPSZ, acc2[1], v.y);
            v.z = fmaf(STEPSZ, acc2[2], v.z);
            v.w = fmaf(STEPSZ, acc2[3], v.w);
            *(float4*)(xdst + off) = v;
        }
    }
    // static cols 32..39 passthrough
    for (int t = tid; t < TM * 2; t += NTHR) {
        int m = t >> 1;
        int n = n0 + m;
        if (n < NN) {
            size_t off = xbase + (size_t)n * DDIM + 32 + (t & 1) * 4;
            *(float4*)(xdst + off) = *(const float4*)(xsrc + off);
        }
    }
}

// ================= fallback f32 path (used only if ws too small) =================
constexpr int FTM = 16;
__global__ __launch_bounds__(256) void step_f32(
    const float* __restrict__ xsrc, float* __restrict__ xdst,
    const int* __restrict__ index,
    const float* __restrict__ W1, const float* __restrict__ b1,
    const float* __restrict__ W2, const float* __restrict__ b2)
{
    __shared__ float z_lds[FTM][160];
    __shared__ float h_lds[FTM][HH];
    __shared__ float fz_lds[FTM][DDYN];
    const int tid = threadIdx.x, tile = blockIdx.x, b = blockIdx.y;
    const int n0 = tile * FTM;
    const int nvalid = min(FTM, NN - n0);
    for (int e = tid; e < FTM * 4 * 10; e += 256) {
        int m = e / 40, r = e % 40, k = r / 10, qq = r % 10;
        float4 v = make_float4(0.f, 0.f, 0.f, 0.f);
        int n = n0 + m;
        if (n < NN) {
            int nb = index[n * 4 + k];
            v = ((const float4*)(xsrc + ((size_t)b * NN + nb) * DDIM))[qq];
        }
        ((float4*)&z_lds[m][k * DDIM])[qq] = v;
    }
    __syncthreads();
    const int c0 = 2 * tid;
    float2 acc[FTM];
    {
        float bx = b1[c0], by = b1[c0 + 1];
        #pragma unroll
        for (int m = 0; m < FTM; ++m) { acc[m].x = bx; acc[m].y = by; }
    }
    for (int kd = 0; kd < 160; kd += 4) {
        float2 w0 = *(const float2*)(W1 + (size_t)(kd + 0) * HH + c0);
        float2 w1 = *(const float2*)(W1 + (size_t)(kd + 1) * HH + c0);
        float2 w2 = *(const float2*)(W1 + (size_t)(kd + 2) * HH + c0);
        float2 w3 = *(const float2*)(W1 + (size_t)(kd + 3) * HH + c0);
        #pragma unroll
        for (int m = 0; m < FTM; ++m) {
            float4 zv = *(const float4*)&z_lds[m][kd];
            acc[m].x = fmaf(zv.x, w0.x, acc[m].x); acc[m].y = fmaf(zv.x, w0.y, acc[m].y);
            acc[m].x = fmaf(zv.y, w1.x, acc[m].x); acc[m].y = fmaf(zv.y, w1.y, acc[m].y);
            acc[m].x = fmaf(zv.z, w2.x, acc[m].x); acc[m].y = fmaf(zv.z, w2.y, acc[m].y);
            acc[m].x = fmaf(zv.w, w3.x, acc[m].x); acc[m].y = fmaf(zv.w, w3.y, acc[m].y);
        }
    }
    #pragma unroll
    for (int m = 0; m < FTM; ++m) {
        h_lds[m][c0]     = gelu_fast(acc[m].x);
        h_lds[m][c0 + 1] = gelu_fast(acc[m].y);
    }
    __syncthreads();
    {
        const int j = tid & 31, mg = tid >> 5;
        float a0 = b2[j], a1 = a0;
        for (int c = 0; c < HH; c += 4) {
            float wa = W2[(size_t)(c + 0) * DDYN + j];
            float wb = W2[(size_t)(c + 1) * DDYN + j];
            float wc = W2[(size_t)(c + 2) * DDYN + j];
            float wd = W2[(size_t)(c + 3) * DDYN + j];
            float4 h0 = *(const float4*)&h_lds[mg][c];
            float4 h1 = *(const float4*)&h_lds[mg + 8][c];
            a0 = fmaf(h0.x, wa, a0); a0 = fmaf(h0.y, wb, a0);
            a0 = fmaf(h0.z, wc, a0); a0 = fmaf(h0.w, wd, a0);
            a1 = fmaf(h1.x, wa, a1); a1 = fmaf(h1.y, wb, a1);
            a1 = fmaf(h1.z, wc, a1); a1 = fmaf(h1.w, wd, a1);
        }
        fz_lds[mg][j] = a0; fz_lds[mg + 8][j] = a1;
    }
    __syncthreads();
    const size_t base = ((size_t)b * NN + n0) * (size_t)DDIM;
    for (int e = tid; e < nvalid * DDIM; e += 256) {
        int m = e / DDIM, d = e % DDIM;
        float v = xsrc[base + e];
        if (d < DDYN) v = fmaf(STEPSZ, fz_lds[m][d], v);
        xdst[base + e] = v;
    }
}

extern "C" void kernel_launch(void* const* d_in, const int* in_sizes, int n_in,
                              void* d_out, int out_size, void* d_ws, size_t ws_size,
                              hipStream_t stream) {
    const float* x   = (const float*)d_in[0];
    const int*   idx = (const int*)  d_in[1];
    const float* W1  = (const float*)d_in[2];
    const float* b1  = (const float*)d_in[3];
    const float* W2  = (const float*)d_in[4];
    const float* b2  = (const float*)d_in[5];
    float* out  = (float*)d_out;
    float* xbuf = (float*)d_ws;

    const size_t need = X_BYTES + (size_t)(W1P_ELEMS + W2P_ELEMS) * 2;
    if (ws_size >= need) {
        unsigned short* W1p = (unsigned short*)((char*)d_ws + X_BYTES);
        unsigned short* W2p = W1p + W1P_ELEMS;
        pack_w1<<<(W1P_ELEMS + 255) / 256, 256, 0, stream>>>(W1, W1p);
        pack_w2<<<(W2P_ELEMS + 255) / 256, 256, 0, stream>>>(W2, W2p);
        dim3 grid(((NN + TM - 1) / TM) * BB), block(NTHR);
        step_mfma<<<grid, block, 0, stream>>>(x,    xbuf, idx, W1p, b1, W2p, b2);
        step_mfma<<<grid, block, 0, stream>>>(xbuf, out,  idx, W1p, b1, W2p, b2);
        step_mfma<<<grid, block, 0, stream>>>(out,  xbuf, idx, W1p, b1, W2p, b2);
        step_mfma<<<grid, block, 0, stream>>>(xbuf, out,  idx, W1p, b1, W2p, b2);
    } else {
        dim3 grid((NN + FTM - 1) / FTM, BB), block(256);
        step_f32<<<grid, block, 0, stream>>>(x,    xbuf, idx, W1, b1, W2, b2);
        step_f32<<<grid, block, 0, stream>>>(xbuf, out,  idx, W1, b1, W2, b2);
        step_f32<<<grid, block, 0, stream>>>(out,  xbuf, idx, W1, b1, W2, b2);
        step_f32<<<grid, block, 0, stream>>>(xbuf, out,  idx, W1, b1, W2, b2);
    }
}